// Round 15
// baseline (77.642 us; speedup 1.0000x reference)
//
#include <hip/hip_runtime.h>
#include <hip/hip_bf16.h>

typedef __bf16 bf16x8 __attribute__((ext_vector_type(8)));
typedef unsigned short u16x8 __attribute__((ext_vector_type(8)));
typedef unsigned int u32x4 __attribute__((ext_vector_type(4)));
typedef float f32x16 __attribute__((ext_vector_type(16)));

#define SLEN 2048
#define DDIM 128
#define NH   32
#define NKVH 8
#define KVB  32
#define MINIT  -1e30f
#define MASKED -3e30f
#define LOG2E  1.4426950408889634f

static __device__ __forceinline__ unsigned short f2bfu(float f) {
  union { float f; unsigned u; } x; x.f = f;
  return (unsigned short)((x.u + 0x7fffu + ((x.u >> 16) & 1u)) >> 16);
}
static __device__ __forceinline__ float bfu2f(unsigned short u) {
  union { unsigned u; float f; } x; x.u = ((unsigned)u) << 16;
  return x.f;
}
static __device__ __forceinline__ unsigned cvt_pk_bf16(float lo, float hi) {
  unsigned r;
  asm("v_cvt_pk_bf16_f32 %0, %1, %2" : "=v"(r) : "v"(lo), "v"(hi));
  return r;
}
static __device__ __forceinline__ f32x16 mfma32(u16x8 a, u16x8 b, f32x16 c) {
  return __builtin_amdgcn_mfma_f32_32x32x16_bf16(
      __builtin_bit_cast(bf16x8, a), __builtin_bit_cast(bf16x8, b), c, 0, 0, 0);
}
// swap lanes 32-63 of a with lanes 0-31 of b
static __device__ __forceinline__ void plswap(unsigned &a, unsigned &b) {
  asm volatile("v_permlane32_swap_b32 %0, %1" : "+v"(a), "+v"(b));
}

// ---- fused prepass: K -> bf16 (blocks 0..1023), V -> bf16 transposed (1024..3071) ----
__global__ __launch_bounds__(256) void conv_kv(const float* __restrict__ k,
                                               const float* __restrict__ v,
                                               unsigned* __restrict__ kdst,
                                               unsigned short* __restrict__ vt) {
  __shared__ unsigned T32[32][17];
  const int bb = blockIdx.x;
  if (bb < 1024) {
    const int i = bb * 256 + threadIdx.x;
    const float4 f0 = ((const float4*)k)[2 * i];
    const float4 f1 = ((const float4*)k)[2 * i + 1];
    u32x4 o = { cvt_pk_bf16(f0.x, f0.y), cvt_pk_bf16(f0.z, f0.w),
                cvt_pk_bf16(f1.x, f1.y), cvt_pk_bf16(f1.z, f1.w) };
    ((u32x4*)kdst)[i] = o;
    return;
  }
  const int b   = bb - 1024;
  const int dt  = b & 3;
  const int st  = (b >> 2) & 63;
  const int kvh = b >> 8;
  const int r  = threadIdx.x >> 3;
  const int cg = threadIdx.x & 7;
  const float4 f = *(const float4*)(v + ((size_t)(kvh * SLEN + st * 32 + r) * DDIM) + dt * 32 + cg * 4);
  T32[r][cg * 2]     = cvt_pk_bf16(f.x, f.y);
  T32[r][cg * 2 + 1] = cvt_pk_bf16(f.z, f.w);
  __syncthreads();
  const int dr = threadIdx.x >> 3;
  const unsigned sel = (dr & 1) ? 0x07060302u : 0x05040100u;
  const unsigned a0 = T32[cg * 4 + 0][dr >> 1], a1 = T32[cg * 4 + 1][dr >> 1];
  const unsigned a2 = T32[cg * 4 + 2][dr >> 1], a3 = T32[cg * 4 + 3][dr >> 1];
  unsigned short* vp = vt + (size_t)kvh * DDIM * SLEN + (size_t)(dt * 32 + dr) * SLEN + st * 32 + cg * 4;
  const unsigned w0 = __builtin_amdgcn_perm(a1, a0, sel);
  const unsigned w1 = __builtin_amdgcn_perm(a3, a2, sel);
  vp[0] = (unsigned short)(w0 & 0xffff);
  vp[1] = (unsigned short)(w0 >> 16);
  vp[2] = (unsigned short)(w1 & 0xffff);
  vp[3] = (unsigned short)(w1 >> 16);
}

// ---- attention: 32x32 MFMA, 32 q-rows/wave, swapped QK^T, in-reg P via permlane ----
template <int NCH>
__global__ __launch_bounds__(256, 2) void attn_fwd(
    const float* __restrict__ q, const unsigned short* __restrict__ kbf,
    const unsigned short* __restrict__ vtg, const float* __restrict__ sinks,
    const int* __restrict__ bwp, float* __restrict__ out,
    unsigned short* __restrict__ pO, float* __restrict__ pm,
    float* __restrict__ pl) {
  constexpr int QBLK = 128;              // 4 waves x 32 q-rows
  constexpr int NQT  = SLEN / QBLK;      // 16
  __shared__ unsigned short Kt[16 * 32 * 8];   // [d-slot][k-row][8el]  8KB
  __shared__ unsigned short Vt2[4 * 128 * 8];  // [k-slot][d-row][8el]  8KB
  __shared__ float SmS[4][32];

  const int tid  = threadIdx.x;
  const int wid  = tid >> 6;
  const int lane = tid & 63;
  const int qc   = lane & 31;            // this lane's q within the wave
  const int hf   = lane >> 5;

  const int B   = blockIdx.x;
  const int x   = B & 7;                 // XCD-resident kvh
  const int j   = B >> 3;
  constexpr int per = 4 * NCH;
  const int qt  = NQT - 1 - (j / per);   // descending: long chunks first
  const int rem = j % per;
  const int hh  = rem / NCH;
  const int c   = rem % NCH;
  const int h   = x * 4 + hh;
  const int kvh = x;
  const int q0  = qt * QBLK;
  const int qrow0 = q0 + wid * 32;
  const int qpos  = qrow0 + qc;

  const int bwv    = bwp[0];
  const int lo_off = (bwv > 0) ? (bwv - 1) : SLEN;

  const int T0 = max(0, q0 - lo_off) >> 5;
  const int T1 = (q0 + QBLK - 1) >> 5;
  const int N  = T1 - T0 + 1;
  const int ch = (N + NCH - 1) / NCH;
  const int Ts = T0 + c * ch;
  const int Te = min(T1, Ts + ch - 1);

  const float c2 = 0.08838834764831845f * LOG2E;

  // ---- Q fragments: qf[dk][j] = Q[qpos][dk*16 + hf*8 + j] (B-operand) ----
  u16x8 qf[8];
  {
    const float* qp = q + ((size_t)(h * SLEN + qpos) * DDIM) + hf * 8;
    #pragma unroll
    for (int dk = 0; dk < 8; ++dk) {
      float4 f0 = *(const float4*)(qp + dk * 16);
      float4 f1 = *(const float4*)(qp + dk * 16 + 4);
      u32x4 t = { cvt_pk_bf16(f0.x, f0.y), cvt_pk_bf16(f0.z, f0.w),
                  cvt_pk_bf16(f1.x, f1.y), cvt_pk_bf16(f1.z, f1.w) };
      qf[dk] = __builtin_bit_cast(u16x8, t);
    }
  }

  float m2 = MINIT;      // log2-domain row max (uniform across both halves)
  float l_ln = 0.0f;     // per-lane partial sum (reduced in epilogue)
  f32x16 oacc[4];
  #pragma unroll
  for (int t = 0; t < 4; ++t)
    #pragma unroll
    for (int r = 0; r < 16; ++r) oacc[t][r] = 0.0f;

  const unsigned short* Kg = kbf + (size_t)kvh * SLEN * DDIM;
  const unsigned short* Vg = vtg + (size_t)kvh * DDIM * SLEN;

  // ---- staging indices: 2 K-chunks + 2 V-chunks per thread ----
  const int i0 = tid, i1 = 256 + tid;
  const int ks0 = i0 >> 5, kr0 = i0 & 31;     // K: slot, row
  const int ks1 = i1 >> 5, kr1 = i1 & 31;
  const int vs0 = i0 >> 7, vd0 = i0 & 127;    // V: k-slot, d-row
  const int vs1 = i1 >> 7, vd1 = i1 & 127;
  const int klo0 = ks0 * 256 + kr0 * 8, klo1 = ks1 * 256 + kr1 * 8;
  const int vlo0 = vs0 * 1024 + vd0 * 8, vlo1 = vs1 * 1024 + vd1 * 8;

  // ---- operand read offsets (elements), both lane-contiguous ----
  int kro[8];
  #pragma unroll
  for (int dk = 0; dk < 8; ++dk) kro[dk] = (dk * 2 + hf) * 256 + qc * 8;

  if (Ts <= Te) {
    const int kbS = Ts * 32, kbE = Te * 32;

    u16x8 pk0, pk1, pv0, pv1;
    pk0 = *(const u16x8*)(Kg + (size_t)(kbS + kr0) * DDIM + ks0 * 8);
    pk1 = *(const u16x8*)(Kg + (size_t)(kbS + kr1) * DDIM + ks1 * 8);
    pv0 = *(const u16x8*)(Vg + (size_t)vd0 * SLEN + kbS + vs0 * 8);
    pv1 = *(const u16x8*)(Vg + (size_t)vd1 * SLEN + kbS + vs1 * 8);

    for (int kb = kbS; kb <= kbE; kb += KVB) {
      __syncthreads();
      *(u16x8*)&Kt[klo0]  = pk0;
      *(u16x8*)&Kt[klo1]  = pk1;
      *(u16x8*)&Vt2[vlo0] = pv0;
      *(u16x8*)&Vt2[vlo1] = pv1;
      __syncthreads();

      {
        const int nb = min(kb + KVB, kbE);
        pk0 = *(const u16x8*)(Kg + (size_t)(nb + kr0) * DDIM + ks0 * 8);
        pk1 = *(const u16x8*)(Kg + (size_t)(nb + kr1) * DDIM + ks1 * 8);
        pv0 = *(const u16x8*)(Vg + (size_t)vd0 * SLEN + nb + vs0 * 8);
        pv1 = *(const u16x8*)(Vg + (size_t)vd1 * SLEN + nb + vs1 * 8);
      }

      if (kb > qrow0 + 31) continue;                 // above causal diag (wave)
      if (kb + KVB - 1 < qrow0 - lo_off) continue;   // before window (wave)

      // ---- QK^T (swapped): S^T[k][q] = K · Q^T, one 32x32 tile ----
      f32x16 sacc;
      #pragma unroll
      for (int r = 0; r < 16; ++r) sacc[r] = 0.0f;
      __builtin_amdgcn_s_setprio(1);
      #pragma unroll
      for (int dk = 0; dk < 8; ++dk)
        sacc = mfma32(*(const u16x8*)&Kt[kro[dk]], qf[dk], sacc);
      __builtin_amdgcn_s_setprio(0);

      // ---- scale + mask; k(reg r) = kb + (r&3) + 8*(r>>2) + 4*hf ----
      float p[16];
      const bool interior = (kb + KVB - 1 <= qrow0) && (kb >= qrow0 + 31 - lo_off);
      if (interior) {
        #pragma unroll
        for (int r = 0; r < 16; ++r) p[r] = sacc[r] * c2;
      } else {
        #pragma unroll
        for (int rq = 0; rq < 4; ++rq)
          #pragma unroll
          for (int ri = 0; ri < 4; ++ri) {
            const int r  = rq * 4 + ri;
            const int kp = kb + ri + 8 * rq + 4 * hf;
            p[r] = ((kp <= qpos) && (kp >= qpos - lo_off)) ? sacc[r] * c2 : MASKED;
          }
      }

      // ---- row max: 15 in-reg + 1 shfl (combine the two k-halves) ----
      float mx = p[0];
      #pragma unroll
      for (int r = 1; r < 16; ++r) mx = fmaxf(mx, p[r]);
      mx = fmaxf(mx, __shfl_xor(mx, 32));

      // ---- defer-max rescale (THR = 8 nats in log2 units) ----
      if (__any(mx > m2 + 11.5415605f)) {
        const float mn   = fmaxf(m2, mx);
        const float corr = exp2f(m2 - mn);
        l_ln *= corr;
        m2 = mn;
        if (hf == 0) SmS[wid][qc] = corr;
        #pragma unroll
        for (int r = 0; r < 16; ++r) {
          const float cr = SmS[wid][(r & 3) + 8 * (r >> 2) + 4 * hf];
          #pragma unroll
          for (int t = 0; t < 4; ++t) oacc[t][r] *= cr;
        }
      }

      // ---- exp2 + per-lane partial sum ----
      float s = 0.0f;
      #pragma unroll
      for (int r = 0; r < 16; ++r) { p[r] = exp2f(p[r] - m2); s += p[r]; }
      l_ln += s;

      // ---- P -> PV A-frags via cvt_pk + permlane32_swap (no LDS) ----
      unsigned A0 = cvt_pk_bf16(p[0],  p[1]),  A1 = cvt_pk_bf16(p[2],  p[3]);
      unsigned B0 = cvt_pk_bf16(p[4],  p[5]),  B1 = cvt_pk_bf16(p[6],  p[7]);
      unsigned C0 = cvt_pk_bf16(p[8],  p[9]),  C1 = cvt_pk_bf16(p[10], p[11]);
      unsigned D0 = cvt_pk_bf16(p[12], p[13]), D1 = cvt_pk_bf16(p[14], p[15]);
      plswap(A0, B0); plswap(A1, B1);   // a0 covers k = 16*0 + hf*8 + 0..7
      plswap(C0, D0); plswap(C1, D1);   // a1 covers k = 16*1 + hf*8 + 0..7
      const u16x8 a0 = __builtin_bit_cast(u16x8, u32x4{A0, A1, B0, B1});
      const u16x8 a1 = __builtin_bit_cast(u16x8, u32x4{C0, C1, D0, D1});

      // ---- PV: O[32q][128d] += P[32q][32k] * V[32k][128d] ----
      __builtin_amdgcn_s_setprio(1);
      #pragma unroll
      for (int t = 0; t < 4; ++t) {
        const u16x8 vb0 = *(const u16x8*)&Vt2[(0 * 2 + hf) * 1024 + (t * 32 + qc) * 8];
        oacc[t] = mfma32(a0, vb0, oacc[t]);
        const u16x8 vb1 = *(const u16x8*)&Vt2[(1 * 2 + hf) * 1024 + (t * 32 + qc) * 8];
        oacc[t] = mfma32(a1, vb1, oacc[t]);
      }
      __builtin_amdgcn_s_setprio(0);
    }
  }

  // ---- lazy l reduction: combine the two k-halves (same q) ----
  l_ln += __shfl_xor(l_ln, 32);

  // ---- epilogue; O reg r -> q-row (r&3)+8*(r>>2)+4*hf, d = t*32 + qc ----
  if (NCH == 1) {
    const float sk2 = sinks[h] * LOG2E;
    const float M  = fmaxf(m2, sk2);
    const float ed = exp2f(m2 - M);
    const float fac = ed / (l_ln * ed + exp2f(sk2 - M));
    if (hf == 0) SmS[wid][qc] = fac;
    __builtin_amdgcn_s_barrier();  // wave-local LDS dependency only; barrier safe (uniform)
    #pragma unroll
    for (int r = 0; r < 16; ++r) {
      const int qr = (r & 3) + 8 * (r >> 2) + 4 * hf;
      const float fr = SmS[wid][qr];
      float* op = out + ((size_t)(h * SLEN + qrow0 + qr) * DDIM) + qc;
      #pragma unroll
      for (int t = 0; t < 4; ++t) op[t * 32] = oacc[t][r] * fr;
    }
  } else {
    const size_t Lb = ((size_t)(h * NQT + qt)) * NCH + c;
    if (hf == 0) {
      pm[Lb * QBLK + wid * 32 + qc] = m2;   // log2 domain
      pl[Lb * QBLK + wid * 32 + qc] = l_ln;
    }
    #pragma unroll
    for (int r = 0; r < 16; ++r) {
      const int qr = (r & 3) + 8 * (r >> 2) + 4 * hf;
      unsigned short* po = pO + (Lb * QBLK + wid * 32 + qr) * 128 + qc;
      #pragma unroll
      for (int t = 0; t < 4; ++t) po[t * 32] = f2bfu(oacc[t][r]);
    }
  }
}

// ---- merge NCH chunk partials + sink (log2-domain stats, XCD-local mapping) ----
template <int NCH, int QBLK, int NQT>
__global__ __launch_bounds__(256) void mergeN(
    const unsigned short* __restrict__ pO, const float* __restrict__ pm,
    const float* __restrict__ pl, const float* __restrict__ sinks,
    float* __restrict__ out) {
  typedef unsigned short u16x8 __attribute__((ext_vector_type(8)));
  const int b   = blockIdx.x;
  const int x   = b & 7;
  const int jj2 = b >> 3;
  const int h   = x * 4 + (jj2 >> 5);
  const int sub = jj2 & 31;
  const int rloc = sub * 64 + (threadIdx.x >> 2);
  const int rid  = h * 2048 + rloc;
  const int d0   = (threadIdx.x & 3) * 32;
  const int qt   = rloc / QBLK;
  const int lr   = rloc % QBLK;
  const size_t base = ((size_t)(h * NQT + qt) * NCH) * QBLK + lr;
  const float sk2 = sinks[h] * LOG2E;
  float mc[NCH], lc[NCH];
  float M = sk2;
  #pragma unroll
  for (int c = 0; c < NCH; ++c) {
    mc[c] = pm[base + (size_t)c * QBLK];
    lc[c] = pl[base + (size_t)c * QBLK];
    M = fmaxf(M, mc[c]);
  }
  float denom = exp2f(sk2 - M);
  float sc[NCH];
  #pragma unroll
  for (int c = 0; c < NCH; ++c) { sc[c] = exp2f(mc[c] - M); denom += lc[c] * sc[c]; }
  const float inv = 1.0f / denom;
  float o[32];
  #pragma unroll
  for (int i = 0; i < 32; ++i) o[i] = 0.f;
  #pragma unroll
  for (int c = 0; c < NCH; ++c) {
    const unsigned short* pp = pO + (base + (size_t)c * QBLK) * 128 + d0;
    const float s = sc[c] * inv;
    #pragma unroll
    for (int i = 0; i < 4; ++i) {
      u16x8 a = *(const u16x8*)(pp + i * 8);
      #pragma unroll
      for (int jj = 0; jj < 8; ++jj) o[i*8+jj] += bfu2f(a[jj]) * s;
    }
  }
  float* op = out + (size_t)rid * 128 + d0;
  #pragma unroll
  for (int i = 0; i < 8; ++i)
    *(float4*)(op + i*4) = make_float4(o[i*4], o[i*4+1], o[i*4+2], o[i*4+3]);
}

extern "C" void kernel_launch(void* const* d_in, const int* in_sizes, int n_in,
                              void* d_out, int out_size, void* d_ws, size_t ws_size,
                              hipStream_t stream) {
  const float* q     = (const float*)d_in[0];
  const float* k     = (const float*)d_in[1];
  const float* v     = (const float*)d_in[2];
  const float* sinks = (const float*)d_in[3];
  const int*   bw    = (const int*)d_in[4];
  float* out = (float*)d_out;

  const size_t kvElems = (size_t)NKVH * SLEN * DDIM;
  unsigned short* kbf = (unsigned short*)d_ws;
  unsigned short* vtg = kbf + kvElems;
  unsigned short* pO  = vtg + kvElems;

  // NCH=2, QBLK=128: partial rows = 32h * 16qt * 2c * 128 -> ~43 MB total
  const size_t nPart2 = (size_t)NH * 16 * 2 * 128;
  const size_t need2  = 4 * kvElems + nPart2 * 128 * 2 + nPart2 * 8;

  conv_kv<<<dim3(1024 + NKVH * 64 * 4), 256, 0, stream>>>(k, v, (unsigned*)kbf, vtg);

  if (ws_size >= need2) {
    float* pm = (float*)(pO + nPart2 * 128);
    float* pl = pm + nPart2;
    attn_fwd<2><<<dim3(1024), 256, 0, stream>>>(q, kbf, vtg, sinks, bw, out, pO, pm, pl);
    mergeN<2, 128, 16><<<dim3(1024), 256, 0, stream>>>(pO, pm, pl, sinks, out);
  } else {
    attn_fwd<1><<<dim3(512), 256, 0, stream>>>(q, kbf, vtg, sinks, bw, out, pO, nullptr, nullptr);
  }
}